// Round 4
// baseline (340.218 us; speedup 1.0000x reference)
//
#include <hip/hip_runtime.h>

// NetVLAD — barrier-free wave-independent bf16 MFMA (round 4).
// B=32, N=4096, D=256, K=128, Dc=64.
// Phase1: 256 blocks (8/batch, 512 rows) x 512 thr (8 waves), 1 blk/CU.
//   Weights frag-order in LDS (read-only after init barrier). Each wave owns
//   16-row tiles end-to-end: X global->reg A-frags, GEMM1 (8 Wa kt), exp (no
//   max pass; |logit|<~6), pack exp bf16 (unnormalized), GEMM2 (4 W1 et),
//   leaky, wave-private LDS transpose, GEMM3 (sq, scaled by 1/sum), AGG via
//   mfma 16x16x16 whose A/B layouts == C-layouts of exp/sq (zero shuffles).
//   NO barriers in the main loop. Epilogue: LDS ds_add_f32 block reduce
//   (aliases dead Wa region), per-block fp32 partials (atomic fallback).
// Layouts (m89/m120-verified):
//   16x16x32: A[m=lane&15][k=quad*8+j], B[k=quad*8+j][n=lane&15],
//             D[row=quad*4+reg][col=lane&15]
//   16x16x16: A[m=lane&15][k=quad*4+j], B[k=quad*4+j][n=lane&15]  (j=0..3)

#define B_   32
#define N_   4096
#define D_   256
#define K_   128
#define DC_  64
#define NEG  0.01f
#define TPB  512
#define NBLK 256
#define BLKPB 8
#define TILES 4

typedef __attribute__((ext_vector_type(8))) short bf16x8;
typedef __attribute__((ext_vector_type(4))) short bf16x4;
typedef __attribute__((ext_vector_type(4))) float f32x4;

// LDS byte offsets (dynamic, 125440 B total -> 1 block/CU)
#define WA_OFF   0        // 8kt x 8ks x 64 x 16 = 65536
#define W1_OFF   65536    // 4et x 8ks x 64 x 16 = 32768
#define W2_OFF   98304    // 4ft x 2ks x 64 x 16 = 8192
#define HB_OFF   106496   // 8 waves x 16 rows x 144 B = 18432
#define MASS_OFF 124928   // 128 floats
#define LDS_BYTES 125440
// epilogue agg buffer aliases WA region: 128 k x 68 stride x 4 B = 34816 B

#if defined(__has_builtin)
#if __has_builtin(__builtin_amdgcn_mfma_f32_16x16x16bf16_1k)
#define HAVE_1K 1
#endif
#endif

__device__ __forceinline__ f32x4 mfma16(bf16x4 a, bf16x4 b, f32x4 c) {
#ifdef HAVE_1K
  return __builtin_amdgcn_mfma_f32_16x16x16bf16_1k(a, b, c, 0, 0, 0);
#else
  asm volatile("v_mfma_f32_16x16x16_bf16 %0, %1, %2, %0\n\ts_nop 7\n\ts_nop 7"
               : "+v"(c) : "v"(a), "v"(b));
  return c;
#endif
}

__device__ __forceinline__ unsigned ppack(float a, float b) {
  union { float f; unsigned u; } A, Bv; A.f = a; Bv.f = b;
  return __builtin_amdgcn_perm(Bv.u + 0x8000u, A.u + 0x8000u, 0x07060302u);
}
__device__ __forceinline__ unsigned short f2bf(float x) {
  union { float f; unsigned u; } v; v.f = x;
  return (unsigned short)((v.u + 0x8000u) >> 16);
}
__device__ __forceinline__ float bflo(unsigned u) {
  union { unsigned u; float f; } z; z.u = u << 16; return z.f;
}
__device__ __forceinline__ float bfhi(unsigned u) {
  union { unsigned u; float f; } z; z.u = u & 0xffff0000u; return z.f;
}

__global__ __launch_bounds__(TPB, 2)
void netvlad_phase1(const float* __restrict__ desc, const float* __restrict__ W1,
                    const float* __restrict__ b1, const float* __restrict__ W2,
                    const float* __restrict__ b2, const float* __restrict__ Wa,
                    const float* __restrict__ ba,
                    float* __restrict__ aggP, float* __restrict__ massP, int mode)
{
  extern __shared__ char smem[];
  const int t    = threadIdx.x;
  const int b    = blockIdx.x >> 3;
  const int blk  = blockIdx.x & 7;
  const int w    = t >> 6;
  const int lane = t & 63;
  const int li   = lane & 15;
  const int quad = lane >> 4;

  // ---- one-time: all weights -> frag-order bf16 LDS (contiguous regions) ----
  for (int p = t; p < 6656; p += TPB) {
    const float* src;
    if (p < 4096) {            // WaF
      int kt = p >> 9, ks = (p >> 6) & 7, L = p & 63;
      src = Wa + (size_t)(kt * 16 + (L & 15)) * D_ + ks * 32 + ((L >> 4) << 3);
    } else if (p < 6144) {     // W1F
      int q = p - 4096; int et = q >> 9, ks = (q >> 6) & 7, L = q & 63;
      src = W1 + (size_t)(et * 16 + (L & 15)) * D_ + ks * 32 + ((L >> 4) << 3);
    } else {                   // W2F
      int q = p - 6144; int ft = q >> 7, ks = (q >> 6) & 1, L = q & 63;
      src = W2 + (size_t)(ft * 16 + (L & 15)) * DC_ + ks * 32 + ((L >> 4) << 3);
    }
    float4 a = ((const float4*)src)[0], c = ((const float4*)src)[1];
    uint4 o;
    o.x = ppack(a.x, a.y); o.y = ppack(a.z, a.w);
    o.z = ppack(c.x, c.y); o.w = ppack(c.z, c.w);
    *reinterpret_cast<uint4*>(smem + (size_t)p * 16) = o;
  }
  if (t < K_) ((float*)(smem + MASS_OFF))[t] = 0.f;

  // biases per lane
  float bar[8], b1r[4], b2r[4];
  #pragma unroll
  for (int kt = 0; kt < 8; ++kt) bar[kt] = ba[kt * 16 + li];
  #pragma unroll
  for (int et = 0; et < 4; ++et) b1r[et] = b1[et * 16 + li];
  #pragma unroll
  for (int ft = 0; ft < 4; ++ft) b2r[ft] = b2[ft * 16 + li];

  f32x4 gacc[8][4];
  #pragma unroll
  for (int kt = 0; kt < 8; ++kt)
    #pragma unroll
    for (int ft = 0; ft < 4; ++ft) gacc[kt][ft] = (f32x4){0.f, 0.f, 0.f, 0.f};
  float massk[8] = {0.f, 0.f, 0.f, 0.f, 0.f, 0.f, 0.f, 0.f};

  __syncthreads();   // weights ready — last barrier until epilogue

  const int hb = HB_OFF + w * 2304;   // wave-private h scratch, 16 rows x 144 B

  for (int tile = 0; tile < TILES; ++tile) {
    const int n0 = blk * 512 + w * 64 + tile * 16;
    const float* xrow = desc + (size_t)(b * N_ + n0 + li) * D_ + quad * 8;

    // ---- X: global -> A-frags (row li, cols ks*32+quad*8..+7) ----
    bf16x8 xa[8];
    #pragma unroll
    for (int hh = 0; hh < 2; ++hh) {
      float4 xf[4][2];
      #pragma unroll
      for (int k2 = 0; k2 < 4; ++k2) {
        const float* s = xrow + (hh * 4 + k2) * 32;
        xf[k2][0] = ((const float4*)s)[0];
        xf[k2][1] = ((const float4*)s)[1];
      }
      #pragma unroll
      for (int k2 = 0; k2 < 4; ++k2) {
        union { uint4 u; bf16x8 v; } z;
        z.u.x = ppack(xf[k2][0].x, xf[k2][0].y);
        z.u.y = ppack(xf[k2][0].z, xf[k2][0].w);
        z.u.z = ppack(xf[k2][1].x, xf[k2][1].y);
        z.u.w = ppack(xf[k2][1].z, xf[k2][1].w);
        xa[hh * 4 + k2] = z.v;
      }
    }

    // ---- pass A: logits over 8 Wa kt, exp, pack (unnormalized) ----
    uint2 aF[8];
    float sr0 = 0.f, sr1 = 0.f, sr2 = 0.f, sr3 = 0.f;
    #pragma unroll
    for (int g = 0; g < 2; ++g) {
      f32x4 acc[4];
      #pragma unroll
      for (int j = 0; j < 4; ++j) {
        float bb = bar[g * 4 + j];
        acc[j] = (f32x4){bb, bb, bb, bb};
      }
      #pragma unroll
      for (int ks = 0; ks < 8; ++ks) {
        #pragma unroll
        for (int j = 0; j < 4; ++j) {
          bf16x8 wb = *reinterpret_cast<const bf16x8*>(
              smem + WA_OFF + (((g * 4 + j) * 8 + ks) * 64 + lane) * 16);
          acc[j] = __builtin_amdgcn_mfma_f32_16x16x32_bf16(xa[ks], wb, acc[j], 0, 0, 0);
        }
      }
      #pragma unroll
      for (int j = 0; j < 4; ++j) {
        float e0 = __expf(acc[j][0]), e1 = __expf(acc[j][1]);
        float e2 = __expf(acc[j][2]), e3 = __expf(acc[j][3]);
        sr0 += e0; sr1 += e1; sr2 += e2; sr3 += e3;
        aF[g * 4 + j].x = ppack(e0, e1);
        aF[g * 4 + j].y = ppack(e2, e3);
      }
    }
    // row sums over li (rows live per (quad,reg); li spans k within tile)
    #pragma unroll
    for (int off = 1; off < 16; off <<= 1) {
      sr0 += __shfl_xor(sr0, off, 64); sr1 += __shfl_xor(sr1, off, 64);
      sr2 += __shfl_xor(sr2, off, 64); sr3 += __shfl_xor(sr3, off, 64);
    }
    const float inv0 = 1.f / sr0, inv1 = 1.f / sr1;
    const float inv2 = 1.f / sr2, inv3 = 1.f / sr3;
    // mass from the SAME bf16-rounded exp values (consistency with AGG)
    #pragma unroll
    for (int kt = 0; kt < 8; ++kt) {
      massk[kt] += bflo(aF[kt].x) * inv0 + bfhi(aF[kt].x) * inv1
                 + bflo(aF[kt].y) * inv2 + bfhi(aF[kt].y) * inv3;
    }

    // ---- pass B: h = leaky(X@W1^T + b1) -> wave-private LDS transpose ----
    {
      f32x4 accH[4];
      #pragma unroll
      for (int et = 0; et < 4; ++et)
        accH[et] = (f32x4){b1r[et], b1r[et], b1r[et], b1r[et]};
      #pragma unroll
      for (int ks = 0; ks < 8; ++ks) {
        #pragma unroll
        for (int et = 0; et < 4; ++et) {
          bf16x8 wb = *reinterpret_cast<const bf16x8*>(
              smem + W1_OFF + ((et * 8 + ks) * 64 + lane) * 16);
          accH[et] = __builtin_amdgcn_mfma_f32_16x16x32_bf16(xa[ks], wb, accH[et], 0, 0, 0);
        }
      }
      #pragma unroll
      for (int et = 0; et < 4; ++et) {
        #pragma unroll
        for (int r = 0; r < 4; ++r) {
          float h = accH[et][r];
          h = h >= 0.f ? h : NEG * h;
          *reinterpret_cast<unsigned short*>(
              smem + hb + (quad * 4 + r) * 144 + (et * 16 + li) * 2) = f2bf(h);
        }
      }
    }
    // same-wave ds_write -> ds_read: ordered by lgkmcnt, no barrier needed
    bf16x8 hA0 = *reinterpret_cast<const bf16x8*>(smem + hb + li * 144 + quad * 16);
    bf16x8 hA1 = *reinterpret_cast<const bf16x8*>(smem + hb + li * 144 + 64 + quad * 16);

    // ---- GEMM3: sq = h @ W2^T + b2, scaled by inv (softmax denom fold) ----
    uint2 sB[4];
    #pragma unroll
    for (int ft = 0; ft < 4; ++ft) {
      f32x4 sacc = (f32x4){b2r[ft], b2r[ft], b2r[ft], b2r[ft]};
      {
        bf16x8 wf0 = *reinterpret_cast<const bf16x8*>(
            smem + W2_OFF + ((ft * 2 + 0) * 64 + lane) * 16);
        sacc = __builtin_amdgcn_mfma_f32_16x16x32_bf16(hA0, wf0, sacc, 0, 0, 0);
        bf16x8 wf1 = *reinterpret_cast<const bf16x8*>(
            smem + W2_OFF + ((ft * 2 + 1) * 64 + lane) * 16);
        sacc = __builtin_amdgcn_mfma_f32_16x16x32_bf16(hA1, wf1, sacc, 0, 0, 0);
      }
      sB[ft].x = ppack(sacc[0] * inv0, sacc[1] * inv1);
      sB[ft].y = ppack(sacc[2] * inv2, sacc[3] * inv3);
    }

    // ---- AGG: gacc[k][d] += exp^T @ (inv*sq); layouts match C-layouts ----
    #pragma unroll
    for (int kt = 0; kt < 8; ++kt) {
      union { uint2 u; bf16x4 v; } av; av.u = aF[kt];
      #pragma unroll
      for (int ft = 0; ft < 4; ++ft) {
        union { uint2 u; bf16x4 v; } bv; bv.u = sB[ft];
        gacc[kt][ft] = mfma16(av.v, bv.v, gacc[kt][ft]);
      }
    }
  }

  // ---- epilogue: block-reduce via LDS f32 atomics (aliases dead Wa) ----
  __syncthreads();
  float* aggL = reinterpret_cast<float*>(smem);     // stride 68 floats per k
  for (int i = t; i < K_ * 68; i += TPB) aggL[i] = 0.f;
  __syncthreads();
  #pragma unroll
  for (int kt = 0; kt < 8; ++kt)
    #pragma unroll
    for (int ft = 0; ft < 4; ++ft)
      #pragma unroll
      for (int r = 0; r < 4; ++r)
        atomicAdd(&aggL[(kt * 16 + quad * 4 + r) * 68 + ft * 16 + li],
                  gacc[kt][ft][r]);
  #pragma unroll
  for (int kt = 0; kt < 8; ++kt) {
    float v = massk[kt];
    v += __shfl_xor(v, 16, 64);
    v += __shfl_xor(v, 32, 64);
    if (lane < 16) atomicAdd((float*)(smem + MASS_OFF) + kt * 16 + li, v);
  }
  __syncthreads();

  if (mode) {
    float* aggB = aggP + (size_t)blockIdx.x * (K_ * DC_);
    for (int i = t; i < (K_ * DC_) / 4; i += TPB) {
      int lin = i * 4, k = lin >> 6, d = lin & 63;
      *reinterpret_cast<float4*>(aggB + lin) =
          *reinterpret_cast<const float4*>(&aggL[k * 68 + d]);
    }
    if (t < K_) massP[blockIdx.x * K_ + t] = ((float*)(smem + MASS_OFF))[t];
  } else {
    float* aggB = aggP + (size_t)b * (K_ * DC_);
    for (int i = t; i < K_ * DC_; i += TPB)
      atomicAdd(&aggB[i], aggL[(i >> 6) * 68 + (i & 63)]);
    if (t < K_) atomicAdd(&massP[b * K_ + t], ((float*)(smem + MASS_OFF))[t]);
  }
}

__global__ __launch_bounds__(1024)
void netvlad_phase2(const float* __restrict__ aggP, const float* __restrict__ massP,
                    const float* __restrict__ centroid, float* __restrict__ out, int P)
{
  __shared__ float v[K_ * DC_];
  __shared__ float ms[K_];
  __shared__ float red[16];
  const int b = blockIdx.x, t = threadIdx.x;
  if (t < K_) {
    float s = 0.f;
    if (P == BLKPB) {
      #pragma unroll
      for (int p = 0; p < BLKPB; ++p) s += massP[(size_t)(b * BLKPB + p) * K_ + t];
    } else s = massP[(size_t)b * K_ + t];
    ms[t] = s;
  }
  __syncthreads();
  float ss = 0.f;
  for (int i = t; i < K_ * DC_; i += 1024) {
    float s = 0.f;
    if (P == BLKPB) {
      #pragma unroll
      for (int p = 0; p < BLKPB; ++p)
        s += aggP[(size_t)(b * BLKPB + p) * (K_ * DC_) + i];
    } else s = aggP[(size_t)b * (K_ * DC_) + i];
    float val = s - ms[i >> 6] * centroid[i];
    v[i] = val;
    ss += val * val;
  }
  #pragma unroll
  for (int off = 32; off > 0; off >>= 1) ss += __shfl_down(ss, off, 64);
  if ((t & 63) == 0) red[t >> 6] = ss;
  __syncthreads();
  if (t == 0) {
    float s = 0.f;
    #pragma unroll
    for (int i = 0; i < 16; ++i) s += red[i];
    red[0] = 1.0f / fmaxf(sqrtf(s), 1e-12f);
  }
  __syncthreads();
  const float inv = red[0];
  for (int i = t; i < K_ * DC_; i += 1024)
    out[(size_t)b * (K_ * DC_) + i] = v[i] * inv;
}

extern "C" void kernel_launch(void* const* d_in, const int* in_sizes, int n_in,
                              void* d_out, int out_size, void* d_ws, size_t ws_size,
                              hipStream_t stream) {
  const float* desc     = (const float*)d_in[0];
  const float* W1       = (const float*)d_in[1];
  const float* b1       = (const float*)d_in[2];
  const float* W2       = (const float*)d_in[3];
  const float* b2       = (const float*)d_in[4];
  const float* Wa       = (const float*)d_in[5];
  const float* ba       = (const float*)d_in[6];
  const float* centroid = (const float*)d_in[7];
  float* out = (float*)d_out;

  const size_t needP = (size_t)NBLK * (K_ * DC_ + K_) * sizeof(float);  // ~8.5 MB
  const int mode = (ws_size >= needP) ? 1 : 0;
  const int P = mode ? BLKPB : 1;

  float* aggP  = (float*)d_ws;
  float* massP = aggP + (size_t)(mode ? NBLK : B_) * (K_ * DC_);
  if (!mode) {
    size_t zbytes = (size_t)B_ * (K_ * DC_ + K_) * sizeof(float);
    hipMemsetAsync(d_ws, 0, zbytes, stream);
  }

  hipFuncSetAttribute(reinterpret_cast<const void*>(netvlad_phase1),
                      hipFuncAttributeMaxDynamicSharedMemorySize, LDS_BYTES);

  netvlad_phase1<<<dim3(NBLK), dim3(TPB), LDS_BYTES, stream>>>(
      desc, W1, b1, W2, b2, Wa, ba, aggP, massP, mode);
  netvlad_phase2<<<dim3(B_), dim3(1024), 0, stream>>>(aggP, massP, centroid, out, P);
}

// Round 5
// 296.676 us; speedup vs baseline: 1.1468x; 1.1468x over previous
//
#include <hip/hip_runtime.h>

// NetVLAD — split design (round 5). B=32, N=4096, D=256, K=128, Dc=64.
// Kernel A (256 blocks x 1024 thr, 4 waves/SIMD): per 16-row wave-tile:
//   X global->A-frags, GEMM1 (logits, 8 Wa kt), exp -> P_t[b,k,n] bf16 (raw),
//   rowsum -> inv (fp32), inv_t bf16; GEMM2 (h), leaky, wave-private LDS
//   transpose; GEMM3 (sq), scale by inv -> LDS transpose -> S_t[b,d,n] bf16.
//   Weights frag-order in LDS (104 KB); NO accumulators, NO mass, NO gacc.
// Kernel B (256 blocks x 256 thr, no LDS): agg[b,k,d] = sum_n P_t*S_t via
//   MFMA with frags loaded DIRECTLY from global (both operands k(=n)-contig,
//   16B/lane). mass via masked inv B-frag. Per-(b,nchunk) fp32 partials.
// Kernel C (32 blocks): reduce 8 partials, vlad = agg - mass*centroid,
//   L2-normalize, write out.
// MFMA 16x16x32 layouts (m89/m120-verified):
//   A: lane holds A[m=lane&15][k=(lane>>4)*8+j]
//   B: lane holds B[k=(lane>>4)*8+j][n=lane&15]
//   C/D: lane holds D[row=(lane>>4)*4+reg][col=lane&15]

#define B_   32
#define N_   4096
#define D_   256
#define K_   128
#define DC_  64
#define NEG  0.01f
#define TPB_A 1024
#define NCH  8          // n-chunks per batch (512 rows each)

typedef __attribute__((ext_vector_type(8))) short bf16x8;
typedef __attribute__((ext_vector_type(4))) float f32x4;

// Kernel A LDS map (dynamic, 143360 B)
#define WA_OFF   0        // 8kt x 8ks x 64 x 16 = 65536
#define W1_OFF   65536    // 4et x 8ks x 64 x 16 = 32768
#define W2_OFF   98304    // 4ft x 2ks x 64 x 16 = 8192
#define HB_OFF   106496   // 16 waves x 2304 B
#define LDSA_BYTES 143360

__device__ __forceinline__ unsigned ppack(float a, float b) {
  union { float f; unsigned u; } A, Bv; A.f = a; Bv.f = b;
  return __builtin_amdgcn_perm(Bv.u + 0x8000u, A.u + 0x8000u, 0x07060302u);
}
__device__ __forceinline__ unsigned short f2bf(float x) {
  union { float f; unsigned u; } v; v.f = x;
  return (unsigned short)((v.u + 0x8000u) >> 16);
}

__global__ __launch_bounds__(TPB_A)
void netvlad_kA(const float* __restrict__ desc, const float* __restrict__ W1,
                const float* __restrict__ b1, const float* __restrict__ W2,
                const float* __restrict__ b2, const float* __restrict__ Wa,
                const float* __restrict__ ba,
                unsigned short* __restrict__ Pt, unsigned short* __restrict__ St,
                unsigned short* __restrict__ invT)
{
  extern __shared__ char smem[];
  const int t    = threadIdx.x;
  const int b    = blockIdx.x >> 3;
  const int nc   = blockIdx.x & 7;
  const int w    = t >> 6;
  const int lane = t & 63;
  const int li   = lane & 15;
  const int quad = lane >> 4;

  // ---- one-time: weights -> frag-order bf16 LDS ----
  for (int p = t; p < 6656; p += TPB_A) {
    const float* src;
    if (p < 4096) {            // WaF
      int kt = p >> 9, ks = (p >> 6) & 7, L = p & 63;
      src = Wa + (size_t)(kt * 16 + (L & 15)) * D_ + ks * 32 + ((L >> 4) << 3);
    } else if (p < 6144) {     // W1F
      int q = p - 4096; int et = q >> 9, ks = (q >> 6) & 7, L = q & 63;
      src = W1 + (size_t)(et * 16 + (L & 15)) * D_ + ks * 32 + ((L >> 4) << 3);
    } else {                   // W2F
      int q = p - 6144; int ft = q >> 7, ks = (q >> 6) & 1, L = q & 63;
      src = W2 + (size_t)(ft * 16 + (L & 15)) * DC_ + ks * 32 + ((L >> 4) << 3);
    }
    float4 a = ((const float4*)src)[0], c = ((const float4*)src)[1];
    uint4 o;
    o.x = ppack(a.x, a.y); o.y = ppack(a.z, a.w);
    o.z = ppack(c.x, c.y); o.w = ppack(c.z, c.w);
    *reinterpret_cast<uint4*>(smem + (size_t)p * 16) = o;
  }

  float bar[8], b1r[4], b2r[4];
  #pragma unroll
  for (int kt = 0; kt < 8; ++kt) bar[kt] = ba[kt * 16 + li];
  #pragma unroll
  for (int et = 0; et < 4; ++et) b1r[et] = b1[et * 16 + li];
  #pragma unroll
  for (int ft = 0; ft < 4; ++ft) b2r[ft] = b2[ft * 16 + li];

  __syncthreads();   // weights ready — only barrier

  const int hb = HB_OFF + w * 2304;   // wave-private scratch

  for (int T = 0; T < 2; ++T) {
    const int n_loc = w * 32 + T * 16;          // 0..511
    const int n_g   = nc * 512 + n_loc;         // within batch
    const float* xrow = desc + ((size_t)b * N_ + n_g + li) * D_ + quad * 8;

    // ---- X: global -> A-frags ----
    bf16x8 xa[8];
    #pragma unroll
    for (int hh = 0; hh < 2; ++hh) {
      float4 xf[4][2];
      #pragma unroll
      for (int k2 = 0; k2 < 4; ++k2) {
        const float* s = xrow + (hh * 4 + k2) * 32;
        xf[k2][0] = ((const float4*)s)[0];
        xf[k2][1] = ((const float4*)s)[1];
      }
      #pragma unroll
      for (int k2 = 0; k2 < 4; ++k2) {
        union { uint4 u; bf16x8 v; } z;
        z.u.x = ppack(xf[k2][0].x, xf[k2][0].y);
        z.u.y = ppack(xf[k2][0].z, xf[k2][0].w);
        z.u.z = ppack(xf[k2][1].x, xf[k2][1].y);
        z.u.w = ppack(xf[k2][1].z, xf[k2][1].w);
        xa[hh * 4 + k2] = z.v;
      }
    }

    // ---- GEMM1: logits over 8 Wa kt; exp; store P_t; rowsum ----
    float sr0 = 0.f, sr1 = 0.f, sr2 = 0.f, sr3 = 0.f;
    #pragma unroll
    for (int g = 0; g < 2; ++g) {
      f32x4 acc[4];
      #pragma unroll
      for (int j = 0; j < 4; ++j) {
        float bb = bar[g * 4 + j];
        acc[j] = (f32x4){bb, bb, bb, bb};
      }
      #pragma unroll
      for (int ks = 0; ks < 8; ++ks) {
        #pragma unroll
        for (int j = 0; j < 4; ++j) {
          bf16x8 wb = *reinterpret_cast<const bf16x8*>(
              smem + WA_OFF + (((g * 4 + j) * 8 + ks) * 64 + lane) * 16);
          acc[j] = __builtin_amdgcn_mfma_f32_16x16x32_bf16(xa[ks], wb, acc[j], 0, 0, 0);
        }
      }
      #pragma unroll
      for (int j = 0; j < 4; ++j) {
        float e0 = __expf(acc[j][0]), e1 = __expf(acc[j][1]);
        float e2 = __expf(acc[j][2]), e3 = __expf(acc[j][3]);
        sr0 += e0; sr1 += e1; sr2 += e2; sr3 += e3;
        // P_t[b][k][n]: k = (g*4+j)*16+li (C-layout col), n = n_g + quad*4 + r
        const int k = (g * 4 + j) * 16 + li;
        uint2 pk; pk.x = ppack(e0, e1); pk.y = ppack(e2, e3);
        *reinterpret_cast<uint2*>(Pt + ((size_t)b * K_ + k) * N_ + n_g + quad * 4) = pk;
      }
    }
    #pragma unroll
    for (int off = 1; off < 16; off <<= 1) {
      sr0 += __shfl_xor(sr0, off, 64); sr1 += __shfl_xor(sr1, off, 64);
      sr2 += __shfl_xor(sr2, off, 64); sr3 += __shfl_xor(sr3, off, 64);
    }
    const float inv0 = 1.f / sr0, inv1 = 1.f / sr1;
    const float inv2 = 1.f / sr2, inv3 = 1.f / sr3;
    if (li == 0) {
      uint2 pk; pk.x = ppack(inv0, inv1); pk.y = ppack(inv2, inv3);
      *reinterpret_cast<uint2*>(invT + (size_t)b * N_ + n_g + quad * 4) = pk;
    }

    // ---- GEMM2: h = leaky(X@W1^T+b1) -> wave-private LDS transpose ----
    {
      f32x4 accH[4];
      #pragma unroll
      for (int et = 0; et < 4; ++et)
        accH[et] = (f32x4){b1r[et], b1r[et], b1r[et], b1r[et]};
      #pragma unroll
      for (int ks = 0; ks < 8; ++ks) {
        #pragma unroll
        for (int et = 0; et < 4; ++et) {
          bf16x8 wb = *reinterpret_cast<const bf16x8*>(
              smem + W1_OFF + ((et * 8 + ks) * 64 + lane) * 16);
          accH[et] = __builtin_amdgcn_mfma_f32_16x16x32_bf16(xa[ks], wb, accH[et], 0, 0, 0);
        }
      }
      #pragma unroll
      for (int et = 0; et < 4; ++et) {
        #pragma unroll
        for (int r = 0; r < 4; ++r) {
          float h = accH[et][r];
          h = h >= 0.f ? h : NEG * h;
          *reinterpret_cast<unsigned short*>(
              smem + hb + (quad * 4 + r) * 144 + (et * 16 + li) * 2) = f2bf(h);
        }
      }
    }
    // same-wave ds ordering: reads below see writes above
    bf16x8 hA0 = *reinterpret_cast<const bf16x8*>(smem + hb + li * 144 + quad * 16);
    bf16x8 hA1 = *reinterpret_cast<const bf16x8*>(smem + hb + li * 144 + 64 + quad * 16);

    // ---- GEMM3: sq = h@W2^T+b2, scale by inv; transpose -> S_t[b][d][n] ----
    #pragma unroll
    for (int ft = 0; ft < 4; ++ft) {
      f32x4 sacc = (f32x4){b2r[ft], b2r[ft], b2r[ft], b2r[ft]};
      bf16x8 wf0 = *reinterpret_cast<const bf16x8*>(
          smem + W2_OFF + ((ft * 2 + 0) * 64 + lane) * 16);
      sacc = __builtin_amdgcn_mfma_f32_16x16x32_bf16(hA0, wf0, sacc, 0, 0, 0);
      bf16x8 wf1 = *reinterpret_cast<const bf16x8*>(
          smem + W2_OFF + ((ft * 2 + 1) * 64 + lane) * 16);
      sacc = __builtin_amdgcn_mfma_f32_16x16x32_bf16(hA1, wf1, sacc, 0, 0, 0);
      // hb2[d][n16]: rows 32 B (16 x bf16); d = ft*16+li, n = quad*4+r
      uint2 pk;
      pk.x = ppack(sacc[0] * inv0, sacc[1] * inv1);
      pk.y = ppack(sacc[2] * inv2, sacc[3] * inv3);
      *reinterpret_cast<uint2*>(smem + hb + (ft * 16 + li) * 32 + quad * 8) = pk;
    }
    // readback 16B slices, store to S_t (16B contiguous in n)
    #pragma unroll
    for (int i = 0; i < 2; ++i) {
      const int s = lane + i * 64;          // s = d*2 + h8
      const int d = s >> 1, h8 = s & 1;
      bf16x8 sv = *reinterpret_cast<const bf16x8*>(smem + hb + s * 16);
      *reinterpret_cast<bf16x8*>(St + ((size_t)b * DC_ + d) * N_ + n_g + h8 * 8) = sv;
    }
  }
}

__global__ __launch_bounds__(256)
void netvlad_kB(const unsigned short* __restrict__ Pt,
                const unsigned short* __restrict__ St,
                const unsigned short* __restrict__ invT,
                float* __restrict__ aggP, float* __restrict__ massP)
{
  const int t    = threadIdx.x;
  const int b    = blockIdx.x >> 3;
  const int nc   = blockIdx.x & 7;
  const int w    = t >> 6;
  const int lane = t & 63;
  const int li   = lane & 15;
  const int quad = lane >> 4;

  f32x4 gacc[2][4], macc[2];
  #pragma unroll
  for (int m = 0; m < 2; ++m) {
    macc[m] = (f32x4){0.f, 0.f, 0.f, 0.f};
    #pragma unroll
    for (int nt = 0; nt < 4; ++nt) gacc[m][nt] = (f32x4){0.f, 0.f, 0.f, 0.f};
  }

  const unsigned short* paBase = Pt + ((size_t)b * K_ + w * 32 + li) * N_;
  const unsigned short* sbBase = St + ((size_t)b * DC_ + li) * N_;
  const unsigned short* ivBase = invT + (size_t)b * N_;

  #pragma unroll 4
  for (int s = 0; s < 16; ++s) {
    const int n0 = nc * 512 + s * 32 + quad * 8;
    bf16x8 a0 = *reinterpret_cast<const bf16x8*>(paBase + n0);
    bf16x8 a1 = *reinterpret_cast<const bf16x8*>(paBase + 16 * N_ + n0);
    bf16x8 bn[4];
    #pragma unroll
    for (int nt = 0; nt < 4; ++nt)
      bn[nt] = *reinterpret_cast<const bf16x8*>(sbBase + nt * 16 * N_ + n0);
    bf16x8 iv = (bf16x8){0,0,0,0,0,0,0,0};
    if (li == 0) iv = *reinterpret_cast<const bf16x8*>(ivBase + n0);
    #pragma unroll
    for (int nt = 0; nt < 4; ++nt) {
      gacc[0][nt] = __builtin_amdgcn_mfma_f32_16x16x32_bf16(a0, bn[nt], gacc[0][nt], 0, 0, 0);
      gacc[1][nt] = __builtin_amdgcn_mfma_f32_16x16x32_bf16(a1, bn[nt], gacc[1][nt], 0, 0, 0);
    }
    macc[0] = __builtin_amdgcn_mfma_f32_16x16x32_bf16(a0, iv, macc[0], 0, 0, 0);
    macc[1] = __builtin_amdgcn_mfma_f32_16x16x32_bf16(a1, iv, macc[1], 0, 0, 0);
  }

  float* ab = aggP + (size_t)(b * NCH + nc) * (K_ * DC_);
  #pragma unroll
  for (int m = 0; m < 2; ++m)
    #pragma unroll
    for (int nt = 0; nt < 4; ++nt)
      #pragma unroll
      for (int r = 0; r < 4; ++r)
        ab[(w * 32 + m * 16 + quad * 4 + r) * DC_ + nt * 16 + li] = gacc[m][nt][r];
  if (li == 0) {
    float* mb = massP + (size_t)(b * NCH + nc) * K_;
    #pragma unroll
    for (int m = 0; m < 2; ++m)
      #pragma unroll
      for (int r = 0; r < 4; ++r)
        mb[w * 32 + m * 16 + quad * 4 + r] = macc[m][r];
  }
}

__global__ __launch_bounds__(1024)
void netvlad_kC(const float* __restrict__ aggP, const float* __restrict__ massP,
                const float* __restrict__ centroid, float* __restrict__ out)
{
  __shared__ float v[K_ * DC_];
  __shared__ float ms[K_];
  __shared__ float red[16];
  const int b = blockIdx.x, t = threadIdx.x;
  if (t < K_) {
    float s = 0.f;
    #pragma unroll
    for (int p = 0; p < NCH; ++p) s += massP[(size_t)(b * NCH + p) * K_ + t];
    ms[t] = s;
  }
  __syncthreads();
  float ss = 0.f;
  for (int i = t; i < K_ * DC_; i += 1024) {
    float s = 0.f;
    #pragma unroll
    for (int p = 0; p < NCH; ++p) s += aggP[(size_t)(b * NCH + p) * (K_ * DC_) + i];
    float val = s - ms[i >> 6] * centroid[i];
    v[i] = val;
    ss += val * val;
  }
  #pragma unroll
  for (int off = 32; off > 0; off >>= 1) ss += __shfl_down(ss, off, 64);
  if ((t & 63) == 0) red[t >> 6] = ss;
  __syncthreads();
  if (t == 0) {
    float s = 0.f;
    #pragma unroll
    for (int i = 0; i < 16; ++i) s += red[i];
    red[0] = 1.0f / fmaxf(sqrtf(s), 1e-12f);
  }
  __syncthreads();
  const float inv = red[0];
  for (int i = t; i < K_ * DC_; i += 1024)
    out[(size_t)b * (K_ * DC_) + i] = v[i] * inv;
}

extern "C" void kernel_launch(void* const* d_in, const int* in_sizes, int n_in,
                              void* d_out, int out_size, void* d_ws, size_t ws_size,
                              hipStream_t stream) {
  const float* desc     = (const float*)d_in[0];
  const float* W1       = (const float*)d_in[1];
  const float* b1       = (const float*)d_in[2];
  const float* W2       = (const float*)d_in[3];
  const float* b2       = (const float*)d_in[4];
  const float* Wa       = (const float*)d_in[5];
  const float* ba       = (const float*)d_in[6];
  const float* centroid = (const float*)d_in[7];
  float* out = (float*)d_out;

  // ws carve-up (bytes):
  //   Pt   : B*K*N  bf16 = 33,554,432
  //   St   : B*Dc*N bf16 = 16,777,216
  //   invT : B*N    bf16 =    262,144
  //   aggP : 256*8192 f32 =  8,388,608
  //   massP: 256*128 f32  =    131,072
  char* p = (char*)d_ws;
  unsigned short* Pt   = (unsigned short*)p;  p += (size_t)B_ * K_ * N_ * 2;
  unsigned short* St   = (unsigned short*)p;  p += (size_t)B_ * DC_ * N_ * 2;
  unsigned short* invT = (unsigned short*)p;  p += (size_t)B_ * N_ * 2;
  float* aggP  = (float*)p;                   p += (size_t)B_ * NCH * K_ * DC_ * 4;
  float* massP = (float*)p;                   p += (size_t)B_ * NCH * K_ * 4;

  hipFuncSetAttribute(reinterpret_cast<const void*>(netvlad_kA),
                      hipFuncAttributeMaxDynamicSharedMemorySize, LDSA_BYTES);

  netvlad_kA<<<dim3(B_ * NCH), dim3(TPB_A), LDSA_BYTES, stream>>>(
      desc, W1, b1, W2, b2, Wa, ba, Pt, St, invT);
  netvlad_kB<<<dim3(B_ * NCH), dim3(256), 0, stream>>>(Pt, St, invT, aggP, massP);
  netvlad_kC<<<dim3(B_), dim3(1024), 0, stream>>>(aggP, massP, centroid, out);
}